// Round 9
// baseline (3093.411 us; speedup 1.0000x reference)
//
#include <hip/hip_runtime.h>

#define EPSF    1e-10f
#define MAXENT  6.93147180559945286f   // ln(1024)
#define SCALEF  0.37796447300922720f   // 1/sqrt(7)

// ---------------- helpers ----------------
__device__ __forceinline__ float wave_sum(float v) {
#pragma unroll
  for (int off = 32; off > 0; off >>= 1) v += __shfl_xor(v, off);
  return v;
}
__device__ __forceinline__ void wave_sum2(float& a, float& b) {
#pragma unroll
  for (int off = 32; off > 0; off >>= 1) {
    a += __shfl_xor(a, off);
    b += __shfl_xor(b, off);
  }
}
__device__ __forceinline__ void fma4(float a, float4 b, float4& c) {
  c.x = fmaf(a, b.x, c.x); c.y = fmaf(a, b.y, c.y);
  c.z = fmaf(a, b.z, c.z); c.w = fmaf(a, b.w, c.w);
}
__device__ __forceinline__ float dot4(float4 a, float4 b, float acc) {
  acc = fmaf(a.x, b.x, acc); acc = fmaf(a.y, b.y, acc);
  acc = fmaf(a.z, b.z, acc); acc = fmaf(a.w, b.w, acc);
  return acc;
}
__device__ __forceinline__ float exp4sum(float4 s) {
  return __expf(s.x) + __expf(s.y) + __expf(s.z) + __expf(s.w);
}
// P0 = (E1*exp(s1) + E2*exp(s2) + EPS)^10, E_h = 0.5/L_h (no-max softmax; |s|<~12 so safe)
__device__ __forceinline__ float p0e(float s1, float s2, float E1, float E2) {
  float p = fmaf(E1, __expf(s1), fmaf(E2, __expf(s2), EPSF));
  float p2 = p * p, p4 = p2 * p2, p5 = p4 * p;
  return p5 * p5;
}

// ---------------- kernel 0: QKV projection (d-major, Q pre-scaled) + R/C init ----------------
__global__ __launch_bounds__(256) void qkv_kernel(
    const float* __restrict__ x,
    const float* __restrict__ Wq, const float* __restrict__ bq,
    const float* __restrict__ Wk, const float* __restrict__ bk,
    const float* __restrict__ Wv, const float* __restrict__ bv,
    float* __restrict__ Qt, float* __restrict__ Kt, float* __restrict__ Vt,
    float* __restrict__ R, float* __restrict__ CA, float* __restrict__ CB) {
  int row = blockIdx.x * 256 + threadIdx.x;     // 65536 rows
  int b = row >> 10, i = row & 1023;
  float xv[14];
#pragma unroll
  for (int k = 0; k < 14; k++) xv[k] = x[row * 14 + k];
#pragma unroll
  for (int d = 0; d < 14; d++) {
    float q = bq[d], kk = bk[d], vv = bv[d];
#pragma unroll
    for (int k = 0; k < 14; k++) {
      q  = fmaf(xv[k], Wq[d * 14 + k], q);
      kk = fmaf(xv[k], Wk[d * 14 + k], kk);
      vv = fmaf(xv[k], Wv[d * 14 + k], vv);
    }
    int o = b * 14336 + d * 1024 + i;
    Qt[o] = q * SCALEF;
    Kt[o] = kk; Vt[o] = vv;
  }
  R[row] = 1.0f;
  CA[row] = 1.0f;
  CB[row] = 1.0f;
}

// ---------------- kernel 1: fused attention + entropy/certainty + E1/E2 ----------------
// 4 rows per wave (kv LDS reads amortized over 4 rows), 32 rows/block, grid 2048
__global__ __launch_bounds__(512) void attn_kernel(
    const float* __restrict__ Qt, const float* __restrict__ Kt, const float* __restrict__ Vt,
    const float* __restrict__ cert_in,
    float* __restrict__ E1o, float* __restrict__ E2o,
    float* __restrict__ attn_o, float* __restrict__ cert_out) {
  __shared__ float4 Kl[3584];                   // 56 KB
  int b = blockIdx.x >> 5;                      // 32 blocks per batch
  int rg = blockIdx.x & 31;                     // 32 rows per block
  int tid = threadIdx.x;
  const float4* Ktb = (const float4*)(Kt + b * 14336);
  for (int idx = tid; idx < 3584; idx += 512) Kl[idx] = Ktb[idx];
  __syncthreads();

  int wave = tid >> 6, lane = tid & 63;
  int i0 = rg * 32 + wave * 4;
  float q[4][14];
#pragma unroll
  for (int rr = 0; rr < 4; rr++)
#pragma unroll
    for (int d = 0; d < 14; d++) q[rr][d] = Qt[b * 14336 + d * 1024 + i0 + rr];

  // pass 1: L per row per head
  float L1[4] = {0, 0, 0, 0}, L2[4] = {0, 0, 0, 0};
#pragma unroll
  for (int t = 0; t < 4; t++) {
    int g = t * 64 + lane;
    float4 kv[7];
#pragma unroll
    for (int d = 0; d < 7; d++) kv[d] = Kl[d * 256 + g];
#pragma unroll
    for (int rr = 0; rr < 4; rr++) {
      float4 s = {0, 0, 0, 0};
#pragma unroll
      for (int d = 0; d < 7; d++) fma4(q[rr][d], kv[d], s);
      L1[rr] += exp4sum(s);
    }
#pragma unroll
    for (int d = 0; d < 7; d++) kv[d] = Kl[(d + 7) * 256 + g];
#pragma unroll
    for (int rr = 0; rr < 4; rr++) {
      float4 s = {0, 0, 0, 0};
#pragma unroll
      for (int d = 0; d < 7; d++) fma4(q[rr][d + 7], kv[d], s);
      L2[rr] += exp4sum(s);
    }
  }
#pragma unroll
  for (int rr = 0; rr < 4; rr++) wave_sum2(L1[rr], L2[rr]);
  float i1[4], i2[4];
#pragma unroll
  for (int rr = 0; rr < 4; rr++) { i1[rr] = 1.0f / L1[rr]; i2[rr] = 1.0f / L2[rr]; }

  // pass 2: recompute scores, accumulate O and entropy
  float acc[4][14];
#pragma unroll
  for (int rr = 0; rr < 4; rr++)
#pragma unroll
    for (int d = 0; d < 14; d++) acc[rr][d] = 0.f;
  float ent[4] = {0, 0, 0, 0};
  const float4* Vtb = (const float4*)(Vt + b * 14336);
#pragma unroll
  for (int t = 0; t < 4; t++) {
    int g = t * 64 + lane;
    float4 kv[7];
    float4 e1[4], e2[4];
#pragma unroll
    for (int d = 0; d < 7; d++) kv[d] = Kl[d * 256 + g];
#pragma unroll
    for (int rr = 0; rr < 4; rr++) {
      float4 s = {0, 0, 0, 0};
#pragma unroll
      for (int d = 0; d < 7; d++) fma4(q[rr][d], kv[d], s);
      e1[rr] = make_float4(__expf(s.x), __expf(s.y), __expf(s.z), __expf(s.w));
    }
#pragma unroll
    for (int d = 0; d < 7; d++) kv[d] = Kl[(d + 7) * 256 + g];
#pragma unroll
    for (int rr = 0; rr < 4; rr++) {
      float4 s = {0, 0, 0, 0};
#pragma unroll
      for (int d = 0; d < 7; d++) fma4(q[rr][d + 7], kv[d], s);
      e2[rr] = make_float4(__expf(s.x), __expf(s.y), __expf(s.z), __expf(s.w));
    }
#pragma unroll
    for (int d = 0; d < 7; d++) {
      float4 vv = Vtb[d * 256 + g];
#pragma unroll
      for (int rr = 0; rr < 4; rr++)
        acc[rr][d] += e1[rr].x * vv.x + e1[rr].y * vv.y + e1[rr].z * vv.z + e1[rr].w * vv.w;
    }
#pragma unroll
    for (int d = 7; d < 14; d++) {
      float4 vv = Vtb[d * 256 + g];
#pragma unroll
      for (int rr = 0; rr < 4; rr++)
        acc[rr][d] += e2[rr].x * vv.x + e2[rr].y * vv.y + e2[rr].z * vv.z + e2[rr].w * vv.w;
    }
#pragma unroll
    for (int rr = 0; rr < 4; rr++) {
      float a;
      a = 0.5f * (e1[rr].x * i1[rr] + e2[rr].x * i2[rr]); ent[rr] -= a * __logf(a + EPSF);
      a = 0.5f * (e1[rr].y * i1[rr] + e2[rr].y * i2[rr]); ent[rr] -= a * __logf(a + EPSF);
      a = 0.5f * (e1[rr].z * i1[rr] + e2[rr].z * i2[rr]); ent[rr] -= a * __logf(a + EPSF);
      a = 0.5f * (e1[rr].w * i1[rr] + e2[rr].w * i2[rr]); ent[rr] -= a * __logf(a + EPSF);
    }
  }
#pragma unroll
  for (int rr = 0; rr < 4; rr += 2) wave_sum2(ent[rr], ent[rr + 1]);
#pragma unroll
  for (int rr = 0; rr < 4; rr++)
#pragma unroll
    for (int d = 0; d < 14; d += 2) wave_sum2(acc[rr][d], acc[rr][d + 1]);

  if (lane == 0) {
#pragma unroll
    for (int rr = 0; rr < 4; rr++) {
      int row = b * 1024 + i0 + rr;
      E1o[row] = 0.5f * i1[rr];
      E2o[row] = 0.5f * i2[rr];
#pragma unroll
      for (int d = 0; d < 14; d++)
        attn_o[row * 14 + d] = acc[rr][d] * (d < 7 ? i1[rr] : i2[rr]);
      cert_out[row] = fmaxf(cert_in[row], 1.0f / (1.0f + __expf(ent[rr] - MAXENT)));
    }
  }
}

// ---------------- kernel 2: output projection ----------------
__global__ __launch_bounds__(256) void proj_kernel(
    const float* __restrict__ attn_o, const float* __restrict__ Wo,
    const float* __restrict__ bo, float* __restrict__ out) {
  int idx = blockIdx.x * 256 + threadIdx.x;     // 917504 = 65536*14
  if (idx >= 917504) return;
  int row = idx / 14, d = idx - row * 14;
  float s = bo[d];
  const float* ar = attn_o + row * 14;
  const float* wr = Wo + d * 14;
#pragma unroll
  for (int k = 0; k < 14; k++) s = fmaf(ar[k], wr[k], s);
  out[idx] = s;
}

// ================= FAST PATH: grouped materialized P0 =================

// precompute P0 for G batches starting at b0; grid = G*32 blocks, 32 rows/block
__global__ __launch_bounds__(512) void p0pre_kernel(
    const float* __restrict__ Qt, const float* __restrict__ Kt,
    const float* __restrict__ E1, const float* __restrict__ E2,
    float* __restrict__ P0, int b0) {
  __shared__ float4 Kl[3584];
  int gb = blockIdx.x >> 5, blk = blockIdx.x & 31;
  int b = b0 + gb;
  int tid = threadIdx.x;
  const float4* Ktb = (const float4*)(Kt + b * 14336);
  for (int idx = tid; idx < 3584; idx += 512) Kl[idx] = Ktb[idx];
  __syncthreads();

  int wave = tid >> 6, lane = tid & 63;
  int i0 = blk * 32 + wave * 4;
  float q[4][14], e1r[4], e2r[4];
#pragma unroll
  for (int rr = 0; rr < 4; rr++) {
#pragma unroll
    for (int d = 0; d < 14; d++) q[rr][d] = Qt[b * 14336 + d * 1024 + i0 + rr];
    e1r[rr] = E1[b * 1024 + i0 + rr];
    e2r[rr] = E2[b * 1024 + i0 + rr];
  }
  float4* P0f4 = (float4*)P0;
#pragma unroll
  for (int t = 0; t < 4; t++) {
    int g = t * 64 + lane;
    float4 kv[14];
#pragma unroll
    for (int d = 0; d < 14; d++) kv[d] = Kl[d * 256 + g];
#pragma unroll
    for (int rr = 0; rr < 4; rr++) {
      float4 s1 = {0,0,0,0}, s2 = {0,0,0,0};
#pragma unroll
      for (int d = 0; d < 7; d++)  fma4(q[rr][d], kv[d], s1);
#pragma unroll
      for (int d = 7; d < 14; d++) fma4(q[rr][d], kv[d], s2);
      float4 pv;
      pv.x = p0e(s1.x, s2.x, e1r[rr], e2r[rr]);
      pv.y = p0e(s1.y, s2.y, e1r[rr], e2r[rr]);
      pv.z = p0e(s1.z, s2.z, e1r[rr], e2r[rr]);
      pv.w = p0e(s1.w, s2.w, e1r[rr], e2r[rr]);
      P0f4[(size_t)(gb * 1024 + i0 + rr) * 256 + g] = pv;
    }
  }
}

// fused Sinkhorn iteration v5: S=32 slices (grid 4 blocks/CU), 4 rows/wave,
// launch_bounds(512,6) caps VGPR so 3 blocks (24 waves) reside per CU —
// concurrency replaces the explicit prefetch pipeline of v4.
#define SINK_LOGS 5
#define SINK_S    32
__global__ __launch_bounds__(512, 6) void sink_fused(
    const float* __restrict__ P0, const float* __restrict__ Cin,
    float* __restrict__ Cout, float* __restrict__ R,
    const float* __restrict__ vprev, float* __restrict__ vcur,
    int b0, int G) {
  __shared__ float Cl[1024];                    // C_{it-1} for this batch
  __shared__ float vbuf[8192];                  // per-wave v partials (32 KB)
  int tid = threadIdx.x;
  int gb = blockIdx.x >> SINK_LOGS, slice = blockIdx.x & (SINK_S - 1);
  int b = b0 + gb;

  // step A: recompute C_{it-1} (redundant per block; deterministic + identical order)
  for (int col = tid; col < 1024; col += 512) {
    float cv = Cin[b * 1024 + col];
    if (vprev) {
      const float* vp = vprev + gb * 1024 + col;
      float v = 0.f;
#pragma unroll
      for (int s = 0; s < SINK_S; s++) v += vp[(size_t)s * G * 1024];
      cv = fminf(cv / fmaf(cv, v, EPSF), 1e37f);
      if (slice == 0) Cout[b * 1024 + col] = cv;
    }
    Cl[col] = cv;
  }
  __syncthreads();

  int wave = tid >> 6, lane = tid & 63;
  int i0 = slice * 32 + wave * 4;               // 32 rows/block, 4 rows/wave
  int rbase = b * 1024 + i0;
  int l0 = lane, l1 = 64 + lane, l2 = 128 + lane, l3 = 192 + lane;
  const float4* Cl4 = (const float4*)Cl;
  float4 c0 = Cl4[l0], c1 = Cl4[l1], c2 = Cl4[l2], c3 = Cl4[l3];
  float4 v0 = {0,0,0,0}, v1 = {0,0,0,0}, v2 = {0,0,0,0}, v3 = {0,0,0,0};
  const float4* base = (const float4*)P0 + (size_t)(gb * 1024 + i0) * 256;

  float rreg[4];
#pragma unroll
  for (int r = 0; r < 4; r++) rreg[r] = R[rbase + r];

#pragma unroll
  for (int r = 0; r < 4; r += 2) {
    const float4* rowA = base + r * 256;
    const float4* rowB = rowA + 256;
    float4 a0 = rowA[l0], a1 = rowA[l1], a2 = rowA[l2], a3 = rowA[l3];
    float4 b0f = rowB[l0], b1f = rowB[l1], b2f = rowB[l2], b3f = rowB[l3];
    float ua = dot4(a3, c3, dot4(a2, c2, dot4(a1, c1, dot4(a0, c0, 0.f))));
    float ub = dot4(b3f, c3, dot4(b2f, c2, dot4(b1f, c1, dot4(b0f, c0, 0.f))));
    wave_sum2(ua, ub);
    float rva = rreg[r], rvb = rreg[r + 1];
    rva = fminf(rva / fmaf(rva, ua, EPSF), 1e37f);
    rvb = fminf(rvb / fmaf(rvb, ub, EPSF), 1e37f);
    if (lane == 0) { R[rbase + r] = rva; R[rbase + r + 1] = rvb; }
    fma4(rva, a0, v0); fma4(rva, a1, v1); fma4(rva, a2, v2); fma4(rva, a3, v3);
    fma4(rvb, b0f, v0); fma4(rvb, b1f, v1); fma4(rvb, b2f, v2); fma4(rvb, b3f, v3);
  }
  // per-wave LDS regions (no atomics, b128 writes), then column sum across 8 waves
  float4* vb4 = (float4*)vbuf;
  vb4[wave * 256 + l0] = v0; vb4[wave * 256 + l1] = v1;
  vb4[wave * 256 + l2] = v2; vb4[wave * 256 + l3] = v3;
  __syncthreads();
  for (int col = tid; col < 1024; col += 512) {
    float v = 0.f;
#pragma unroll
    for (int w = 0; w < 8; w++) v += vbuf[w * 1024 + col];
    vcur[(size_t)(slice * G + gb) * 1024 + col] = v;
  }
}

// final C_20 = f(C_19, v_20)
__global__ __launch_bounds__(256) void cfinal_kernel(
    const float* __restrict__ Cin, float* __restrict__ Cfin,
    const float* __restrict__ vprev, int b0, int G) {
  int idx = blockIdx.x * 256 + threadIdx.x;     // < G*1024
  int gb = idx >> 10, col = idx & 1023;
  const float* vp = vprev + gb * 1024 + col;
  float v = 0.f;
#pragma unroll
  for (int s = 0; s < SINK_S; s++) v += vp[(size_t)s * G * 1024];
  int o = (b0 + gb) * 1024 + col;
  float cv = Cin[o];
  Cfin[o] = fminf(cv / fmaf(cv, v, EPSF), 1e37f);
}

// argmax over stored P0 * C + permutation gather; grid = G*128
__global__ __launch_bounds__(512) void argmaxP_kernel(
    const float* __restrict__ P0, const float* __restrict__ Cg,
    const int* __restrict__ perm, float* __restrict__ perm_out, int b0) {
  int gb = blockIdx.x >> 7, rg = blockIdx.x & 127;
  int b = b0 + gb;
  int tid = threadIdx.x;
  int wave = tid >> 6, lane = tid & 63;
  int i = rg * 8 + wave;
  const float4* Cb = (const float4*)(Cg + b * 1024);
  const float4* Prow = (const float4*)P0 + (size_t)(gb * 1024 + i) * 256;

  float best = -1.0f;
  int bj = 0;
#pragma unroll
  for (int t = 0; t < 4; t++) {
    int g = t * 64 + lane;
    float4 pv = Prow[g], cv = Cb[g];
    float val;
    val = pv.x * cv.x; if (val > best) { best = val; bj = 4 * g + 0; }
    val = pv.y * cv.y; if (val > best) { best = val; bj = 4 * g + 1; }
    val = pv.z * cv.z; if (val > best) { best = val; bj = 4 * g + 2; }
    val = pv.w * cv.w; if (val > best) { best = val; bj = 4 * g + 3; }
  }
#pragma unroll
  for (int off = 32; off > 0; off >>= 1) {
    float ob = __shfl_xor(best, off);
    int oj = __shfl_xor(bj, off);
    if (ob > best || (ob == best && oj < bj)) { best = ob; bj = oj; }
  }
  if (lane == 0) perm_out[b * 1024 + i] = (float)perm[b * 1024 + bj];
}

// ================= FALLBACK PATH (round-3, recompute) =================

__global__ __launch_bounds__(512) void sinkA_kernel(
    const float* __restrict__ Qt, const float* __restrict__ Kt,
    const float* __restrict__ E1, const float* __restrict__ E2,
    const float* __restrict__ C, float* __restrict__ R) {
  __shared__ float4 Kl[3584];
  int b = blockIdx.x >> 5, blk = blockIdx.x & 31;
  int tid = threadIdx.x;
  const float4* Ktb = (const float4*)(Kt + b * 14336);
  for (int idx = tid; idx < 3584; idx += 512) Kl[idx] = Ktb[idx];
  __syncthreads();
  int wave = tid >> 6, lane = tid & 63;
  int i0 = blk * 32 + wave * 4;
  float q[4][14], e1r[4], e2r[4], u[4];
#pragma unroll
  for (int rr = 0; rr < 4; rr++) {
#pragma unroll
    for (int d = 0; d < 14; d++) q[rr][d] = Qt[b * 14336 + d * 1024 + i0 + rr];
    e1r[rr] = E1[b * 1024 + i0 + rr];
    e2r[rr] = E2[b * 1024 + i0 + rr];
    u[rr] = 0.f;
  }
  const float4* Cb = (const float4*)(C + b * 1024);
#pragma unroll
  for (int t = 0; t < 4; t++) {
    int g = t * 64 + lane;
    float4 kv[14];
#pragma unroll
    for (int d = 0; d < 14; d++) kv[d] = Kl[d * 256 + g];
    float4 cv = Cb[g];
#pragma unroll
    for (int rr = 0; rr < 4; rr++) {
      float4 s1 = {0,0,0,0}, s2 = {0,0,0,0};
#pragma unroll
      for (int d = 0; d < 7; d++)  fma4(q[rr][d], kv[d], s1);
#pragma unroll
      for (int d = 7; d < 14; d++) fma4(q[rr][d], kv[d], s2);
      u[rr] += p0e(s1.x, s2.x, e1r[rr], e2r[rr]) * cv.x;
      u[rr] += p0e(s1.y, s2.y, e1r[rr], e2r[rr]) * cv.y;
      u[rr] += p0e(s1.z, s2.z, e1r[rr], e2r[rr]) * cv.z;
      u[rr] += p0e(s1.w, s2.w, e1r[rr], e2r[rr]) * cv.w;
    }
  }
#pragma unroll
  for (int rr = 0; rr < 4; rr++) u[rr] = wave_sum(u[rr]);
  if (lane == 0) {
#pragma unroll
    for (int rr = 0; rr < 4; rr++) {
      int o = b * 1024 + i0 + rr;
      float rv = R[o];
      R[o] = fminf(rv / fmaf(rv, u[rr], EPSF), 1e37f);
    }
  }
}

__global__ __launch_bounds__(512) void sinkB_kernel(
    const float* __restrict__ Qt, const float* __restrict__ Kt,
    const float* __restrict__ E1, const float* __restrict__ E2,
    const float* __restrict__ R, float* __restrict__ C) {
  __shared__ float4 Ql[3584];
  int b = blockIdx.x >> 5, blk = blockIdx.x & 31;
  int tid = threadIdx.x;
  const float4* Qtb = (const float4*)(Qt + b * 14336);
  for (int idx = tid; idx < 3584; idx += 512) Ql[idx] = Qtb[idx];
  __syncthreads();
  int wave = tid >> 6, lane = tid & 63;
  int j0 = blk * 32 + wave * 4;
  float kk[4][14], v[4];
#pragma unroll
  for (int rr = 0; rr < 4; rr++) {
#pragma unroll
    for (int d = 0; d < 14; d++) kk[rr][d] = Kt[b * 14336 + d * 1024 + j0 + rr];
    v[rr] = 0.f;
  }
  const float4* E1b = (const float4*)(E1 + b * 1024);
  const float4* E2b = (const float4*)(E2 + b * 1024);
  const float4* Rb  = (const float4*)(R + b * 1024);
#pragma unroll
  for (int t = 0; t < 4; t++) {
    int g = t * 64 + lane;
    float4 qv[14];
#pragma unroll
    for (int d = 0; d < 14; d++) qv[d] = Ql[d * 256 + g];
    float4 e1v = E1b[g], e2v = E2b[g], rv = Rb[g];
#pragma unroll
    for (int rr = 0; rr < 4; rr++) {
      float4 s1 = {0,0,0,0}, s2 = {0,0,0,0};
#pragma unroll
      for (int d = 0; d < 7; d++)  fma4(kk[rr][d], qv[d], s1);
#pragma unroll
      for (int d = 7; d < 14; d++) fma4(kk[rr][d], qv[d], s2);
      v[rr] += p0e(s1.x, s2.x, e1v.x, e2v.x) * rv.x;
      v[rr] += p0e(s1.y, s2.y, e1v.y, e2v.y) * rv.y;
      v[rr] += p0e(s1.z, s2.z, e1v.z, e2v.z) * rv.z;
      v[rr] += p0e(s1.w, s2.w, e1v.w, e2v.w) * rv.w;
    }
  }
#pragma unroll
  for (int rr = 0; rr < 4; rr++) v[rr] = wave_sum(v[rr]);
  if (lane == 0) {
#pragma unroll
    for (int rr = 0; rr < 4; rr++) {
      int o = b * 1024 + j0 + rr;
      float cv = C[o];
      C[o] = fminf(cv / fmaf(cv, v[rr], EPSF), 1e37f);
    }
  }
}

__global__ __launch_bounds__(512) void argmax_kernel(
    const float* __restrict__ Qt, const float* __restrict__ Kt,
    const float* __restrict__ E1, const float* __restrict__ E2,
    const float* __restrict__ C, const int* __restrict__ perm,
    float* __restrict__ perm_out) {
  __shared__ float4 Kl[3584];
  int b = blockIdx.x >> 7, rg = blockIdx.x & 127;
  int tid = threadIdx.x;
  const float4* Ktb = (const float4*)(Kt + b * 14336);
  for (int idx = tid; idx < 3584; idx += 512) Kl[idx] = Ktb[idx];
  __syncthreads();
  int wave = tid >> 6, lane = tid & 63;
  int i = rg * 8 + wave;
  int row = b * 1024 + i;
  float q[14];
#pragma unroll
  for (int d = 0; d < 14; d++) q[d] = Qt[b * 14336 + d * 1024 + i];
  float e1r = E1[row], e2r = E2[row];
  const float4* Cb = (const float4*)(C + b * 1024);
  float best = -1.0f;
  int bj = 0;
#pragma unroll
  for (int t = 0; t < 4; t++) {
    int g = t * 64 + lane;
    float4 kv[14];
#pragma unroll
    for (int d = 0; d < 14; d++) kv[d] = Kl[d * 256 + g];
    float4 cv = Cb[g];
    float4 s1 = {0,0,0,0}, s2 = {0,0,0,0};
#pragma unroll
    for (int d = 0; d < 7; d++)  fma4(q[d], kv[d], s1);
#pragma unroll
    for (int d = 7; d < 14; d++) fma4(q[d], kv[d], s2);
    float val;
    val = p0e(s1.x, s2.x, e1r, e2r) * cv.x; if (val > best) { best = val; bj = 4 * g + 0; }
    val = p0e(s1.y, s2.y, e1r, e2r) * cv.y; if (val > best) { best = val; bj = 4 * g + 1; }
    val = p0e(s1.z, s2.z, e1r, e2r) * cv.z; if (val > best) { best = val; bj = 4 * g + 2; }
    val = p0e(s1.w, s2.w, e1r, e2r) * cv.w; if (val > best) { best = val; bj = 4 * g + 3; }
  }
#pragma unroll
  for (int off = 32; off > 0; off >>= 1) {
    float ob = __shfl_xor(best, off);
    int oj = __shfl_xor(bj, off);
    if (ob > best || (ob == best && oj < bj)) { best = ob; bj = oj; }
  }
  if (lane == 0) perm_out[row] = (float)perm[b * 1024 + bj];
}

// ---------------- launch ----------------
extern "C" void kernel_launch(void* const* d_in, const int* in_sizes, int n_in,
                              void* d_out, int out_size, void* d_ws, size_t ws_size,
                              hipStream_t stream) {
  const float* x    = (const float*)d_in[0];
  const float* cert = (const float*)d_in[1];
  const int*   perm = (const int*)d_in[2];
  const float* Wq = (const float*)d_in[3];
  const float* bq = (const float*)d_in[4];
  const float* Wk = (const float*)d_in[5];
  const float* bk = (const float*)d_in[6];
  const float* Wv = (const float*)d_in[7];
  const float* bv = (const float*)d_in[8];
  const float* Wo = (const float*)d_in[9];
  const float* bo = (const float*)d_in[10];

  float* out      = (float*)d_out;            // 917504
  float* cert_out = out + 917504;             // 65536
  float* perm_out = out + 983040;             // 65536

  float* ws = (float*)d_ws;
  float* Qt = ws;                    // 917504
  float* Kt = Qt + 917504;           // 917504
  float* Vt = Kt + 917504;           // 917504
  float* E1 = Vt + 917504;           // 65536
  float* E2 = E1 + 65536;            // 65536
  float* R  = E2 + 65536;            // 65536
  float* CA = R + 65536;             // 65536  (C ping)
  float* CB = CA + 65536;            // 65536  (C pong)
  float* attn_o = CB + 65536;        // 917504  (base ends: 3,997,696 floats)
  float* vpp0   = attn_o + 917504;   // SINK_S*G*1024 (fast path)
  // vpp1, P0 laid out after vpp0 depending on G

  // choose batch-group size G by available workspace
  // need(G) = base + 2*SINK_S*G*1024 (vpart x2) + G*1048576 (P0)
  size_t base_f = 3997696u;
  size_t avail_f = (ws_size / 4 > base_f) ? (ws_size / 4 - base_f) : 0;
  size_t perG = 2u * SINK_S * 1024 + 1048576u;  // 65536 + 1048576 floats per batch
  int G = 0;
  if (avail_f >= 64 * perG) G = 64;
  else if (avail_f >= 32 * perG) G = 32;
  else if (avail_f >= 16 * perG) G = 16;

  float* Cbuf[2] = {CA, CB};

  qkv_kernel<<<256, 256, 0, stream>>>(x, Wq, bq, Wk, bk, Wv, bv, Qt, Kt, Vt, R, CA, CB);
  attn_kernel<<<2048, 512, 0, stream>>>(Qt, Kt, Vt, cert, E1, E2, attn_o, cert_out);
  proj_kernel<<<3584, 256, 0, stream>>>(attn_o, Wo, bo, out);

  if (G >= 16) {
    float* vpp[2] = {vpp0, vpp0 + (size_t)SINK_S * G * 1024};
    float* P0 = vpp0 + (size_t)2 * SINK_S * G * 1024;
    for (int b0 = 0; b0 < 64; b0 += G) {
      p0pre_kernel<<<G * 32, 512, 0, stream>>>(Qt, Kt, E1, E2, P0, b0);
      for (int it = 1; it <= 20; it++) {
        const float* vprev = (it == 1) ? nullptr : vpp[(it - 1) & 1];
        float* vcur = vpp[it & 1];
        const float* Cin = Cbuf[it & 1];
        float* Cout = Cbuf[(it + 1) & 1];
        sink_fused<<<G * SINK_S, 512, 0, stream>>>(P0, Cin, Cout, R, vprev, vcur, b0, G);
      }
      // C_20 = f(C_19, v_20); C_19 is in Cbuf[1], v_20 in vpp[0]; write to Cbuf[0]
      cfinal_kernel<<<G * 4, 256, 0, stream>>>(Cbuf[1], Cbuf[0], vpp[0], b0, G);
      argmaxP_kernel<<<G * 128, 512, 0, stream>>>(P0, Cbuf[0], perm, perm_out, b0);
    }
  } else {
    for (int it = 0; it < 20; it++) {
      sinkA_kernel<<<2048, 512, 0, stream>>>(Qt, Kt, E1, E2, CA, R);
      sinkB_kernel<<<2048, 512, 0, stream>>>(Qt, Kt, E1, E2, R, CA);
    }
    argmax_kernel<<<8192, 512, 0, stream>>>(Qt, Kt, E1, E2, CA, perm, perm_out);
  }
}

// Round 10
// 1426.118 us; speedup vs baseline: 2.1691x; 2.1691x over previous
//
#include <hip/hip_runtime.h>

#define EPSF    1e-10f
#define MAXENT  6.93147180559945286f   // ln(1024)
#define SCALEF  0.37796447300922720f   // 1/sqrt(7)

// ---------------- helpers ----------------
__device__ __forceinline__ float wave_sum(float v) {
#pragma unroll
  for (int off = 32; off > 0; off >>= 1) v += __shfl_xor(v, off);
  return v;
}
__device__ __forceinline__ void wave_sum2(float& a, float& b) {
#pragma unroll
  for (int off = 32; off > 0; off >>= 1) {
    a += __shfl_xor(a, off);
    b += __shfl_xor(b, off);
  }
}
__device__ __forceinline__ void fma4(float a, float4 b, float4& c) {
  c.x = fmaf(a, b.x, c.x); c.y = fmaf(a, b.y, c.y);
  c.z = fmaf(a, b.z, c.z); c.w = fmaf(a, b.w, c.w);
}
__device__ __forceinline__ float dot4(float4 a, float4 b, float acc) {
  acc = fmaf(a.x, b.x, acc); acc = fmaf(a.y, b.y, acc);
  acc = fmaf(a.z, b.z, acc); acc = fmaf(a.w, b.w, acc);
  return acc;
}
__device__ __forceinline__ float exp4sum(float4 s) {
  return __expf(s.x) + __expf(s.y) + __expf(s.z) + __expf(s.w);
}
// P0 = (E1*exp(s1) + E2*exp(s2) + EPS)^10, E_h = 0.5/L_h (no-max softmax; |s|<~12 so safe)
__device__ __forceinline__ float p0e(float s1, float s2, float E1, float E2) {
  float p = fmaf(E1, __expf(s1), fmaf(E2, __expf(s2), EPSF));
  float p2 = p * p, p4 = p2 * p2, p5 = p4 * p;
  return p5 * p5;
}

// ---------------- kernel 0: QKV projection (d-major, Q pre-scaled) + R/C init ----------------
__global__ __launch_bounds__(256) void qkv_kernel(
    const float* __restrict__ x,
    const float* __restrict__ Wq, const float* __restrict__ bq,
    const float* __restrict__ Wk, const float* __restrict__ bk,
    const float* __restrict__ Wv, const float* __restrict__ bv,
    float* __restrict__ Qt, float* __restrict__ Kt, float* __restrict__ Vt,
    float* __restrict__ R, float* __restrict__ CA, float* __restrict__ CB) {
  int row = blockIdx.x * 256 + threadIdx.x;     // 65536 rows
  int b = row >> 10, i = row & 1023;
  float xv[14];
#pragma unroll
  for (int k = 0; k < 14; k++) xv[k] = x[row * 14 + k];
#pragma unroll
  for (int d = 0; d < 14; d++) {
    float q = bq[d], kk = bk[d], vv = bv[d];
#pragma unroll
    for (int k = 0; k < 14; k++) {
      q  = fmaf(xv[k], Wq[d * 14 + k], q);
      kk = fmaf(xv[k], Wk[d * 14 + k], kk);
      vv = fmaf(xv[k], Wv[d * 14 + k], vv);
    }
    int o = b * 14336 + d * 1024 + i;
    Qt[o] = q * SCALEF;
    Kt[o] = kk; Vt[o] = vv;
  }
  R[row] = 1.0f;
  CA[row] = 1.0f;
  CB[row] = 1.0f;
}

// ---------------- kernel 1: fused attention (round-8 proven: 2 rows/wave) ----------------
__global__ __launch_bounds__(512) void attn_kernel(
    const float* __restrict__ Qt, const float* __restrict__ Kt, const float* __restrict__ Vt,
    const float* __restrict__ cert_in,
    float* __restrict__ E1o, float* __restrict__ E2o,
    float* __restrict__ attn_o, float* __restrict__ cert_out) {
  __shared__ float4 Kl[3584];                   // 56 KB
  int b = blockIdx.x >> 6;
  int rg = blockIdx.x & 63;
  int tid = threadIdx.x;
  const float4* Ktb = (const float4*)(Kt + b * 14336);
  for (int idx = tid; idx < 3584; idx += 512) Kl[idx] = Ktb[idx];
  __syncthreads();

  int wave = tid >> 6, lane = tid & 63;
  int i0 = rg * 16 + wave * 2;
  float q0[14], q1[14];
#pragma unroll
  for (int d = 0; d < 14; d++) {
    q0[d] = Qt[b * 14336 + d * 1024 + i0];
    q1[d] = Qt[b * 14336 + d * 1024 + i0 + 1];
  }

  float L10 = 0.f, L20 = 0.f, L11 = 0.f, L21 = 0.f;
#pragma unroll
  for (int t = 0; t < 4; t++) {
    int g = t * 64 + lane;
    float4 kv[7];
#pragma unroll
    for (int d = 0; d < 7; d++) kv[d] = Kl[d * 256 + g];
    float4 sa = {0,0,0,0}, sb = {0,0,0,0};
#pragma unroll
    for (int d = 0; d < 7; d++) { fma4(q0[d], kv[d], sa); fma4(q1[d], kv[d], sb); }
    L10 += exp4sum(sa); L11 += exp4sum(sb);
#pragma unroll
    for (int d = 0; d < 7; d++) kv[d] = Kl[(d + 7) * 256 + g];
    sa = make_float4(0,0,0,0); sb = make_float4(0,0,0,0);
#pragma unroll
    for (int d = 0; d < 7; d++) { fma4(q0[d + 7], kv[d], sa); fma4(q1[d + 7], kv[d], sb); }
    L20 += exp4sum(sa); L21 += exp4sum(sb);
  }
  L10 = wave_sum(L10); L20 = wave_sum(L20);
  L11 = wave_sum(L11); L21 = wave_sum(L21);
  float i10 = 1.0f / L10, i20 = 1.0f / L20, i11 = 1.0f / L11, i21 = 1.0f / L21;

  float acc0[14], acc1[14];
#pragma unroll
  for (int d = 0; d < 14; d++) { acc0[d] = 0.f; acc1[d] = 0.f; }
  float ent0 = 0.f, ent1 = 0.f;
  const float4* Vtb = (const float4*)(Vt + b * 14336);
#pragma unroll
  for (int t = 0; t < 4; t++) {
    int g = t * 64 + lane;
    float4 kv[7];
#pragma unroll
    for (int d = 0; d < 7; d++) kv[d] = Kl[d * 256 + g];
    float4 sa = {0,0,0,0}, sb = {0,0,0,0};
#pragma unroll
    for (int d = 0; d < 7; d++) { fma4(q0[d], kv[d], sa); fma4(q1[d], kv[d], sb); }
    float4 e10 = make_float4(__expf(sa.x), __expf(sa.y), __expf(sa.z), __expf(sa.w));
    float4 e11 = make_float4(__expf(sb.x), __expf(sb.y), __expf(sb.z), __expf(sb.w));
#pragma unroll
    for (int d = 0; d < 7; d++) kv[d] = Kl[(d + 7) * 256 + g];
    sa = make_float4(0,0,0,0); sb = make_float4(0,0,0,0);
#pragma unroll
    for (int d = 0; d < 7; d++) { fma4(q0[d + 7], kv[d], sa); fma4(q1[d + 7], kv[d], sb); }
    float4 e20 = make_float4(__expf(sa.x), __expf(sa.y), __expf(sa.z), __expf(sa.w));
    float4 e21 = make_float4(__expf(sb.x), __expf(sb.y), __expf(sb.z), __expf(sb.w));
#pragma unroll
    for (int d = 0; d < 7; d++) {
      float4 vv = Vtb[d * 256 + g];
      acc0[d] += e10.x * vv.x + e10.y * vv.y + e10.z * vv.z + e10.w * vv.w;
      acc1[d] += e11.x * vv.x + e11.y * vv.y + e11.z * vv.z + e11.w * vv.w;
    }
#pragma unroll
    for (int d = 7; d < 14; d++) {
      float4 vv = Vtb[d * 256 + g];
      acc0[d] += e20.x * vv.x + e20.y * vv.y + e20.z * vv.z + e20.w * vv.w;
      acc1[d] += e21.x * vv.x + e21.y * vv.y + e21.z * vv.z + e21.w * vv.w;
    }
    float a;
    a = 0.5f * (e10.x * i10 + e20.x * i20); ent0 -= a * __logf(a + EPSF);
    a = 0.5f * (e10.y * i10 + e20.y * i20); ent0 -= a * __logf(a + EPSF);
    a = 0.5f * (e10.z * i10 + e20.z * i20); ent0 -= a * __logf(a + EPSF);
    a = 0.5f * (e10.w * i10 + e20.w * i20); ent0 -= a * __logf(a + EPSF);
    a = 0.5f * (e11.x * i11 + e21.x * i21); ent1 -= a * __logf(a + EPSF);
    a = 0.5f * (e11.y * i11 + e21.y * i21); ent1 -= a * __logf(a + EPSF);
    a = 0.5f * (e11.z * i11 + e21.z * i21); ent1 -= a * __logf(a + EPSF);
    a = 0.5f * (e11.w * i11 + e21.w * i21); ent1 -= a * __logf(a + EPSF);
  }
  ent0 = wave_sum(ent0); ent1 = wave_sum(ent1);
#pragma unroll
  for (int d = 0; d < 14; d++) { acc0[d] = wave_sum(acc0[d]); acc1[d] = wave_sum(acc1[d]); }

  if (lane == 0) {
    int row0 = b * 1024 + i0;
    E1o[row0] = 0.5f * i10;  E2o[row0] = 0.5f * i20;
    E1o[row0 + 1] = 0.5f * i11; E2o[row0 + 1] = 0.5f * i21;
#pragma unroll
    for (int d = 0; d < 14; d++) {
      attn_o[row0 * 14 + d] = acc0[d] * (d < 7 ? i10 : i20);
      attn_o[(row0 + 1) * 14 + d] = acc1[d] * (d < 7 ? i11 : i21);
    }
    cert_out[row0] = fmaxf(cert_in[row0], 1.0f / (1.0f + __expf(ent0 - MAXENT)));
    cert_out[row0 + 1] = fmaxf(cert_in[row0 + 1], 1.0f / (1.0f + __expf(ent1 - MAXENT)));
  }
}

// ---------------- kernel 2: output projection ----------------
__global__ __launch_bounds__(256) void proj_kernel(
    const float* __restrict__ attn_o, const float* __restrict__ Wo,
    const float* __restrict__ bo, float* __restrict__ out) {
  int idx = blockIdx.x * 256 + threadIdx.x;     // 917504 = 65536*14
  if (idx >= 917504) return;
  int row = idx / 14, d = idx - row * 14;
  float s = bo[d];
  const float* ar = attn_o + row * 14;
  const float* wr = Wo + d * 14;
#pragma unroll
  for (int k = 0; k < 14; k++) s = fmaf(ar[k], wr[k], s);
  out[idx] = s;
}

// ================= FAST PATH: grouped materialized P0 =================

// fused P0 precompute + Sinkhorn iteration 1 (C_0 = 1):
// computes P0, u = rowsum (bit-identical to dot with C=1), R_1, and v_1 partials
// (32-row slices -> vpart has 32 slices for iteration 1). Kl LDS reused for v-merge.
__global__ __launch_bounds__(512) void p0sink1_kernel(
    const float* __restrict__ Qt, const float* __restrict__ Kt,
    const float* __restrict__ E1, const float* __restrict__ E2,
    float* __restrict__ P0, float* __restrict__ R,
    float* __restrict__ vpart, int b0, int G) {
  __shared__ float4 Kl[3584];                   // 56 KB: K tile, then reused as v-merge buf
  int gb = blockIdx.x >> 5, blk = blockIdx.x & 31;
  int b = b0 + gb;
  int tid = threadIdx.x;
  const float4* Ktb = (const float4*)(Kt + b * 14336);
  for (int idx = tid; idx < 3584; idx += 512) Kl[idx] = Ktb[idx];
  __syncthreads();

  int wave = tid >> 6, lane = tid & 63;
  int i0 = blk * 32 + wave * 4;
  float q[4][14], e1r[4], e2r[4], u[4];
#pragma unroll
  for (int rr = 0; rr < 4; rr++) {
#pragma unroll
    for (int d = 0; d < 14; d++) q[rr][d] = Qt[b * 14336 + d * 1024 + i0 + rr];
    e1r[rr] = E1[b * 1024 + i0 + rr];
    e2r[rr] = E2[b * 1024 + i0 + rr];
    u[rr] = 0.f;
  }
  float4* P0f4 = (float4*)P0;
#pragma unroll
  for (int t = 0; t < 4; t++) {
    int g = t * 64 + lane;
    float4 kv[14];
#pragma unroll
    for (int d = 0; d < 14; d++) kv[d] = Kl[d * 256 + g];
#pragma unroll
    for (int rr = 0; rr < 4; rr++) {
      float4 s1 = {0,0,0,0}, s2 = {0,0,0,0};
#pragma unroll
      for (int d = 0; d < 7; d++)  fma4(q[rr][d], kv[d], s1);
#pragma unroll
      for (int d = 7; d < 14; d++) fma4(q[rr][d], kv[d], s2);
      float4 pv;
      pv.x = p0e(s1.x, s2.x, e1r[rr], e2r[rr]);
      pv.y = p0e(s1.y, s2.y, e1r[rr], e2r[rr]);
      pv.z = p0e(s1.z, s2.z, e1r[rr], e2r[rr]);
      pv.w = p0e(s1.w, s2.w, e1r[rr], e2r[rr]);
      P0f4[(size_t)(gb * 1024 + i0 + rr) * 256 + g] = pv;
      // u accumulation: same element order as sink's dot4 chain with C=1
      u[rr] += pv.x; u[rr] += pv.y; u[rr] += pv.z; u[rr] += pv.w;
    }
  }
  wave_sum2(u[0], u[1]); wave_sum2(u[2], u[3]);
  float rv[4];
#pragma unroll
  for (int rr = 0; rr < 4; rr++) {
    float r0 = 1.0f;                            // R_0 = 1
    rv[rr] = fminf(r0 / fmaf(r0, u[rr], EPSF), 1e37f);
  }
  if (lane == 0) {
#pragma unroll
    for (int rr = 0; rr < 4; rr++) R[b * 1024 + i0 + rr] = rv[rr];
  }
  // v_1 partials: re-read own just-written P0 rows (same-thread addresses, L2-hot)
  int l0 = lane, l1 = 64 + lane, l2 = 128 + lane, l3 = 192 + lane;
  float4 v0 = {0,0,0,0}, v1 = {0,0,0,0}, v2 = {0,0,0,0}, v3 = {0,0,0,0};
  const float4* base = P0f4 + (size_t)(gb * 1024 + i0) * 256;
#pragma unroll
  for (int rr = 0; rr < 4; rr++) {
    const float4* row = base + rr * 256;
    float4 a0 = row[l0], a1 = row[l1], a2 = row[l2], a3 = row[l3];
    fma4(rv[rr], a0, v0); fma4(rv[rr], a1, v1); fma4(rv[rr], a2, v2); fma4(rv[rr], a3, v3);
  }
  __syncthreads();                              // done with Kl as K tile
  float* vbuf = (float*)Kl;
  float4* vb4 = (float4*)vbuf;
  vb4[wave * 256 + l0] = v0; vb4[wave * 256 + l1] = v1;
  vb4[wave * 256 + l2] = v2; vb4[wave * 256 + l3] = v3;
  __syncthreads();
  for (int col = tid; col < 1024; col += 512) {
    float v = 0.f;
#pragma unroll
    for (int w = 0; w < 8; w++) v += vbuf[w * 1024 + col];
    vpart[(size_t)(blk * G + gb) * 1024 + col] = v;
  }
}

// fused Sinkhorn iteration (round-8 v4 + runtime Sprev + float4 vprev sum):
// each block recomputes C_{it-1} from prev v-partials (slice-0 persists it), then
// u = P0.C, R update, v partials. 1 launch per iteration.
#define SINK_LOGS 4
#define SINK_S    16
__global__ __launch_bounds__(512) void sink_fused(
    const float* __restrict__ P0, const float* __restrict__ Cin,
    float* __restrict__ Cout, float* __restrict__ R,
    const float* __restrict__ vprev, float* __restrict__ vcur,
    int b0, int G, int Sprev) {
  __shared__ float Cl[1024];                    // C_{it-1} for this batch
  __shared__ float vbuf[8192];                  // per-wave v partials (32 KB)
  int tid = threadIdx.x;
  int gb = blockIdx.x >> SINK_LOGS, slice = blockIdx.x & (SINK_S - 1);
  int b = b0 + gb;

  // step A: recompute C_{it-1} (float4; threads 0..255 cover 1024 cols)
  if (tid < 256) {
    float4 cv = ((const float4*)(Cin + b * 1024))[tid];
    const float4* vp = (const float4*)vprev + (size_t)gb * 256 + tid;
    float4 v = {0, 0, 0, 0};
#pragma unroll 4
    for (int s = 0; s < Sprev; s++) {
      float4 t = vp[(size_t)s * G * 256];
      v.x += t.x; v.y += t.y; v.z += t.z; v.w += t.w;
    }
    cv.x = fminf(cv.x / fmaf(cv.x, v.x, EPSF), 1e37f);
    cv.y = fminf(cv.y / fmaf(cv.y, v.y, EPSF), 1e37f);
    cv.z = fminf(cv.z / fmaf(cv.z, v.z, EPSF), 1e37f);
    cv.w = fminf(cv.w / fmaf(cv.w, v.w, EPSF), 1e37f);
    if (slice == 0) ((float4*)(Cout + b * 1024))[tid] = cv;
    ((float4*)Cl)[tid] = cv;
  }
  __syncthreads();

  int wave = tid >> 6, lane = tid & 63;
  int i0 = slice * 64 + wave * 8;               // 64 rows/block, 8 rows/wave
  int rbase = b * 1024 + i0;
  int l0 = lane, l1 = 64 + lane, l2 = 128 + lane, l3 = 192 + lane;
  const float4* Cl4 = (const float4*)Cl;
  float4 c0 = Cl4[l0], c1 = Cl4[l1], c2 = Cl4[l2], c3 = Cl4[l3];
  float4 v0 = {0,0,0,0}, v1 = {0,0,0,0}, v2 = {0,0,0,0}, v3 = {0,0,0,0};
  const float4* base = (const float4*)P0 + (size_t)(gb * 1024 + i0) * 256;

  float rreg[8];
#pragma unroll
  for (int r = 0; r < 8; r++) rreg[r] = R[rbase + r];

  // software-pipelined pairs with next-pair prefetch (round-8 proven)
  float4 a0 = base[l0], a1 = base[l1], a2 = base[l2], a3 = base[l3];
  float4 b0f = base[256 + l0], b1f = base[256 + l1], b2f = base[256 + l2], b3f = base[256 + l3];

#pragma unroll
  for (int r = 0; r < 8; r += 2) {
    float4 na0, na1, na2, na3, nb0, nb1, nb2, nb3;
    if (r + 2 < 8) {
      const float4* nxt = base + (r + 2) * 256;
      na0 = nxt[l0]; na1 = nxt[l1]; na2 = nxt[l2]; na3 = nxt[l3];
      nb0 = nxt[256 + l0]; nb1 = nxt[256 + l1]; nb2 = nxt[256 + l2]; nb3 = nxt[256 + l3];
    }
    float ua = dot4(a3, c3, dot4(a2, c2, dot4(a1, c1, dot4(a0, c0, 0.f))));
    float ub = dot4(b3f, c3, dot4(b2f, c2, dot4(b1f, c1, dot4(b0f, c0, 0.f))));
    wave_sum2(ua, ub);
    float rva = rreg[r], rvb = rreg[r + 1];
    rva = fminf(rva / fmaf(rva, ua, EPSF), 1e37f);
    rvb = fminf(rvb / fmaf(rvb, ub, EPSF), 1e37f);
    if (lane == 0) { R[rbase + r] = rva; R[rbase + r + 1] = rvb; }
    fma4(rva, a0, v0); fma4(rva, a1, v1); fma4(rva, a2, v2); fma4(rva, a3, v3);
    fma4(rvb, b0f, v0); fma4(rvb, b1f, v1); fma4(rvb, b2f, v2); fma4(rvb, b3f, v3);
    if (r + 2 < 8) {
      a0 = na0; a1 = na1; a2 = na2; a3 = na3;
      b0f = nb0; b1f = nb1; b2f = nb2; b3f = nb3;
    }
  }
  // per-wave LDS regions (no atomics, b128 writes), then column sum across 8 waves
  float4* vb4 = (float4*)vbuf;
  vb4[wave * 256 + l0] = v0; vb4[wave * 256 + l1] = v1;
  vb4[wave * 256 + l2] = v2; vb4[wave * 256 + l3] = v3;
  __syncthreads();
  for (int col = tid; col < 1024; col += 512) {
    float v = 0.f;
#pragma unroll
    for (int w = 0; w < 8; w++) v += vbuf[w * 1024 + col];
    vcur[(size_t)(slice * G + gb) * 1024 + col] = v;
  }
}

// final C_20 = f(C_19, v_20)  (v_20 has SINK_S=16 slices)
__global__ __launch_bounds__(256) void cfinal_kernel(
    const float* __restrict__ Cin, float* __restrict__ Cfin,
    const float* __restrict__ vprev, int b0, int G) {
  int idx = blockIdx.x * 256 + threadIdx.x;     // < G*1024
  int gb = idx >> 10, col = idx & 1023;
  const float* vp = vprev + gb * 1024 + col;
  float v = 0.f;
#pragma unroll
  for (int s = 0; s < SINK_S; s++) v += vp[(size_t)s * G * 1024];
  int o = (b0 + gb) * 1024 + col;
  float cv = Cin[o];
  Cfin[o] = fminf(cv / fmaf(cv, v, EPSF), 1e37f);
}

// argmax over stored P0 * C + permutation gather; grid = G*128
__global__ __launch_bounds__(512) void argmaxP_kernel(
    const float* __restrict__ P0, const float* __restrict__ Cg,
    const int* __restrict__ perm, float* __restrict__ perm_out, int b0) {
  int gb = blockIdx.x >> 7, rg = blockIdx.x & 127;
  int b = b0 + gb;
  int tid = threadIdx.x;
  int wave = tid >> 6, lane = tid & 63;
  int i = rg * 8 + wave;
  const float4* Cb = (const float4*)(Cg + b * 1024);
  const float4* Prow = (const float4*)P0 + (size_t)(gb * 1024 + i) * 256;

  float best = -1.0f;
  int bj = 0;
#pragma unroll
  for (int t = 0; t < 4; t++) {
    int g = t * 64 + lane;
    float4 pv = Prow[g], cv = Cb[g];
    float val;
    val = pv.x * cv.x; if (val > best) { best = val; bj = 4 * g + 0; }
    val = pv.y * cv.y; if (val > best) { best = val; bj = 4 * g + 1; }
    val = pv.z * cv.z; if (val > best) { best = val; bj = 4 * g + 2; }
    val = pv.w * cv.w; if (val > best) { best = val; bj = 4 * g + 3; }
  }
#pragma unroll
  for (int off = 32; off > 0; off >>= 1) {
    float ob = __shfl_xor(best, off);
    int oj = __shfl_xor(bj, off);
    if (ob > best || (ob == best && oj < bj)) { best = ob; bj = oj; }
  }
  if (lane == 0) perm_out[b * 1024 + i] = (float)perm[b * 1024 + bj];
}

// ================= FALLBACK PATH (round-3, recompute) =================

__global__ __launch_bounds__(512) void sinkA_kernel(
    const float* __restrict__ Qt, const float* __restrict__ Kt,
    const float* __restrict__ E1, const float* __restrict__ E2,
    const float* __restrict__ C, float* __restrict__ R) {
  __shared__ float4 Kl[3584];
  int b = blockIdx.x >> 5, blk = blockIdx.x & 31;
  int tid = threadIdx.x;
  const float4* Ktb = (const float4*)(Kt + b * 14336);
  for (int idx = tid; idx < 3584; idx += 512) Kl[idx] = Ktb[idx];
  __syncthreads();
  int wave = tid >> 6, lane = tid & 63;
  int i0 = blk * 32 + wave * 4;
  float q[4][14], e1r[4], e2r[4], u[4];
#pragma unroll
  for (int rr = 0; rr < 4; rr++) {
#pragma unroll
    for (int d = 0; d < 14; d++) q[rr][d] = Qt[b * 14336 + d * 1024 + i0 + rr];
    e1r[rr] = E1[b * 1024 + i0 + rr];
    e2r[rr] = E2[b * 1024 + i0 + rr];
    u[rr] = 0.f;
  }
  const float4* Cb = (const float4*)(C + b * 1024);
#pragma unroll
  for (int t = 0; t < 4; t++) {
    int g = t * 64 + lane;
    float4 kv[14];
#pragma unroll
    for (int d = 0; d < 14; d++) kv[d] = Kl[d * 256 + g];
    float4 cv = Cb[g];
#pragma unroll
    for (int rr = 0; rr < 4; rr++) {
      float4 s1 = {0,0,0,0}, s2 = {0,0,0,0};
#pragma unroll
      for (int d = 0; d < 7; d++)  fma4(q[rr][d], kv[d], s1);
#pragma unroll
      for (int d = 7; d < 14; d++) fma4(q[rr][d], kv[d], s2);
      u[rr] += p0e(s1.x, s2.x, e1r[rr], e2r[rr]) * cv.x;
      u[rr] += p0e(s1.y, s2.y, e1r[rr], e2r[rr]) * cv.y;
      u[rr] += p0e(s1.z, s2.z, e1r[rr], e2r[rr]) * cv.z;
      u[rr] += p0e(s1.w, s2.w, e1r[rr], e2r[rr]) * cv.w;
    }
  }
#pragma unroll
  for (int rr = 0; rr < 4; rr++) u[rr] = wave_sum(u[rr]);
  if (lane == 0) {
#pragma unroll
    for (int rr = 0; rr < 4; rr++) {
      int o = b * 1024 + i0 + rr;
      float rv = R[o];
      R[o] = fminf(rv / fmaf(rv, u[rr], EPSF), 1e37f);
    }
  }
}

__global__ __launch_bounds__(512) void sinkB_kernel(
    const float* __restrict__ Qt, const float* __restrict__ Kt,
    const float* __restrict__ E1, const float* __restrict__ E2,
    const float* __restrict__ R, float* __restrict__ C) {
  __shared__ float4 Ql[3584];
  int b = blockIdx.x >> 5, blk = blockIdx.x & 31;
  int tid = threadIdx.x;
  const float4* Qtb = (const float4*)(Qt + b * 14336);
  for (int idx = tid; idx < 3584; idx += 512) Ql[idx] = Qtb[idx];
  __syncthreads();
  int wave = tid >> 6, lane = tid & 63;
  int j0 = blk * 32 + wave * 4;
  float kk[4][14], v[4];
#pragma unroll
  for (int rr = 0; rr < 4; rr++) {
#pragma unroll
    for (int d = 0; d < 14; d++) kk[rr][d] = Kt[b * 14336 + d * 1024 + j0 + rr];
    v[rr] = 0.f;
  }
  const float4* E1b = (const float4*)(E1 + b * 1024);
  const float4* E2b = (const float4*)(E2 + b * 1024);
  const float4* Rb  = (const float4*)(R + b * 1024);
#pragma unroll
  for (int t = 0; t < 4; t++) {
    int g = t * 64 + lane;
    float4 qv[14];
#pragma unroll
    for (int d = 0; d < 14; d++) qv[d] = Ql[d * 256 + g];
    float4 e1v = E1b[g], e2v = E2b[g], rv = Rb[g];
#pragma unroll
    for (int rr = 0; rr < 4; rr++) {
      float4 s1 = {0,0,0,0}, s2 = {0,0,0,0};
#pragma unroll
      for (int d = 0; d < 7; d++)  fma4(kk[rr][d], qv[d], s1);
#pragma unroll
      for (int d = 7; d < 14; d++) fma4(kk[rr][d], qv[d], s2);
      v[rr] += p0e(s1.x, s2.x, e1v.x, e2v.x) * rv.x;
      v[rr] += p0e(s1.y, s2.y, e1v.y, e2v.y) * rv.y;
      v[rr] += p0e(s1.z, s2.z, e1v.z, e2v.z) * rv.z;
      v[rr] += p0e(s1.w, s2.w, e1v.w, e2v.w) * rv.w;
    }
  }
#pragma unroll
  for (int rr = 0; rr < 4; rr++) v[rr] = wave_sum(v[rr]);
  if (lane == 0) {
#pragma unroll
    for (int rr = 0; rr < 4; rr++) {
      int o = b * 1024 + j0 + rr;
      float cv = C[o];
      C[o] = fminf(cv / fmaf(cv, v[rr], EPSF), 1e37f);
    }
  }
}

__global__ __launch_bounds__(512) void argmax_kernel(
    const float* __restrict__ Qt, const float* __restrict__ Kt,
    const float* __restrict__ E1, const float* __restrict__ E2,
    const float* __restrict__ C, const int* __restrict__ perm,
    float* __restrict__ perm_out) {
  __shared__ float4 Kl[3584];
  int b = blockIdx.x >> 7, rg = blockIdx.x & 127;
  int tid = threadIdx.x;
  const float4* Ktb = (const float4*)(Kt + b * 14336);
  for (int idx = tid; idx < 3584; idx += 512) Kl[idx] = Ktb[idx];
  __syncthreads();
  int wave = tid >> 6, lane = tid & 63;
  int i = rg * 8 + wave;
  int row = b * 1024 + i;
  float q[14];
#pragma unroll
  for (int d = 0; d < 14; d++) q[d] = Qt[b * 14336 + d * 1024 + i];
  float e1r = E1[row], e2r = E2[row];
  const float4* Cb = (const float4*)(C + b * 1024);
  float best = -1.0f;
  int bj = 0;
#pragma unroll
  for (int t = 0; t < 4; t++) {
    int g = t * 64 + lane;
    float4 kv[14];
#pragma unroll
    for (int d = 0; d < 14; d++) kv[d] = Kl[d * 256 + g];
    float4 cv = Cb[g];
    float4 s1 = {0,0,0,0}, s2 = {0,0,0,0};
#pragma unroll
    for (int d = 0; d < 7; d++)  fma4(q[d], kv[d], s1);
#pragma unroll
    for (int d = 7; d < 14; d++) fma4(q[d], kv[d], s2);
    float val;
    val = p0e(s1.x, s2.x, e1r, e2r) * cv.x; if (val > best) { best = val; bj = 4 * g + 0; }
    val = p0e(s1.y, s2.y, e1r, e2r) * cv.y; if (val > best) { best = val; bj = 4 * g + 1; }
    val = p0e(s1.z, s2.z, e1r, e2r) * cv.z; if (val > best) { best = val; bj = 4 * g + 2; }
    val = p0e(s1.w, s2.w, e1r, e2r) * cv.w; if (val > best) { best = val; bj = 4 * g + 3; }
  }
#pragma unroll
  for (int off = 32; off > 0; off >>= 1) {
    float ob = __shfl_xor(best, off);
    int oj = __shfl_xor(bj, off);
    if (ob > best || (ob == best && oj < bj)) { best = ob; bj = oj; }
  }
  if (lane == 0) perm_out[row] = (float)perm[b * 1024 + bj];
}

// ---------------- launch ----------------
extern "C" void kernel_launch(void* const* d_in, const int* in_sizes, int n_in,
                              void* d_out, int out_size, void* d_ws, size_t ws_size,
                              hipStream_t stream) {
  const float* x    = (const float*)d_in[0];
  const float* cert = (const float*)d_in[1];
  const int*   perm = (const int*)d_in[2];
  const float* Wq = (const float*)d_in[3];
  const float* bq = (const float*)d_in[4];
  const float* Wk = (const float*)d_in[5];
  const float* bk = (const float*)d_in[6];
  const float* Wv = (const float*)d_in[7];
  const float* bv = (const float*)d_in[8];
  const float* Wo = (const float*)d_in[9];
  const float* bo = (const float*)d_in[10];

  float* out      = (float*)d_out;            // 917504
  float* cert_out = out + 917504;             // 65536
  float* perm_out = out + 983040;             // 65536

  float* ws = (float*)d_ws;
  float* Qt = ws;                    // 917504
  float* Kt = Qt + 917504;           // 917504
  float* Vt = Kt + 917504;           // 917504
  float* E1 = Vt + 917504;           // 65536
  float* E2 = E1 + 65536;            // 65536
  float* R  = E2 + 65536;            // 65536
  float* CA = R + 65536;             // 65536  (C ping)
  float* CB = CA + 65536;            // 65536  (C pong)
  float* attn_o = CB + 65536;        // 917504  (base ends: 3,997,696 floats)
  float* vpp0   = attn_o + 917504;   // 32*G*1024 each buffer (v_1 needs 32 slices)

  // choose batch-group size G by available workspace
  // need(G) = base + 2*32*G*1024 (vpart x2) + G*1048576 (P0)
  size_t base_f = 3997696u;
  size_t avail_f = (ws_size / 4 > base_f) ? (ws_size / 4 - base_f) : 0;
  size_t perG = 2u * 32 * 1024 + 1048576u;      // 65536 + 1048576 floats per batch
  int G = 0;
  if (avail_f >= 64 * perG) G = 64;
  else if (avail_f >= 32 * perG) G = 32;
  else if (avail_f >= 16 * perG) G = 16;

  float* Cbuf[2] = {CA, CB};

  qkv_kernel<<<256, 256, 0, stream>>>(x, Wq, bq, Wk, bk, Wv, bv, Qt, Kt, Vt, R, CA, CB);
  attn_kernel<<<4096, 512, 0, stream>>>(Qt, Kt, Vt, cert, E1, E2, attn_o, cert_out);
  proj_kernel<<<3584, 256, 0, stream>>>(attn_o, Wo, bo, out);

  if (G >= 16) {
    float* vpp[2] = {vpp0, vpp0 + (size_t)32 * G * 1024};
    float* P0 = vpp0 + (size_t)2 * 32 * G * 1024;
    for (int b0 = 0; b0 < 64; b0 += G) {
      // iteration 1 fused with P0 precompute; writes v_1 (32 slices) into vpp[1]
      p0sink1_kernel<<<G * 32, 512, 0, stream>>>(Qt, Kt, E1, E2, P0, R, vpp[1], b0, G);
      for (int it = 2; it <= 20; it++) {
        const float* vprev = vpp[(it - 1) & 1];
        float* vcur = vpp[it & 1];
        const float* Cin = Cbuf[it & 1];
        float* Cout = Cbuf[(it + 1) & 1];
        int Sprev = (it == 2) ? 32 : 16;
        sink_fused<<<G * SINK_S, 512, 0, stream>>>(P0, Cin, Cout, R, vprev, vcur, b0, G, Sprev);
      }
      // C_20 = f(C_19, v_20); C_19 in Cbuf[1], v_20 (16 slices) in vpp[0] -> Cbuf[0]
      cfinal_kernel<<<G * 4, 256, 0, stream>>>(Cbuf[1], Cbuf[0], vpp[0], b0, G);
      argmaxP_kernel<<<G * 128, 512, 0, stream>>>(P0, Cbuf[0], perm, perm_out, b0);
    }
  } else {
    for (int it = 0; it < 20; it++) {
      sinkA_kernel<<<2048, 512, 0, stream>>>(Qt, Kt, E1, E2, CA, R);
      sinkB_kernel<<<2048, 512, 0, stream>>>(Qt, Kt, E1, E2, R, CA);
    }
    argmax_kernel<<<8192, 512, 0, stream>>>(Qt, Kt, E1, E2, CA, perm, perm_out);
  }
}

// Round 11
// 1422.661 us; speedup vs baseline: 2.1744x; 1.0024x over previous
//
#include <hip/hip_runtime.h>

#define EPSF    1e-10f
#define MAXENT  6.93147180559945286f   // ln(1024)
#define SCALEF  0.37796447300922720f   // 1/sqrt(7)

// ---------------- helpers ----------------
__device__ __forceinline__ float wave_sum(float v) {
#pragma unroll
  for (int off = 32; off > 0; off >>= 1) v += __shfl_xor(v, off);
  return v;
}
__device__ __forceinline__ void wave_sum2(float& a, float& b) {
#pragma unroll
  for (int off = 32; off > 0; off >>= 1) {
    a += __shfl_xor(a, off);
    b += __shfl_xor(b, off);
  }
}
__device__ __forceinline__ void fma4(float a, float4 b, float4& c) {
  c.x = fmaf(a, b.x, c.x); c.y = fmaf(a, b.y, c.y);
  c.z = fmaf(a, b.z, c.z); c.w = fmaf(a, b.w, c.w);
}
__device__ __forceinline__ float dot4(float4 a, float4 b, float acc) {
  acc = fmaf(a.x, b.x, acc); acc = fmaf(a.y, b.y, acc);
  acc = fmaf(a.z, b.z, acc); acc = fmaf(a.w, b.w, acc);
  return acc;
}
__device__ __forceinline__ float4 exp4(float4 s) {
  return make_float4(__expf(s.x), __expf(s.y), __expf(s.z), __expf(s.w));
}
// P0 = (E1*exp(s1) + E2*exp(s2) + EPS)^10, E_h = 0.5/L_h (no-max softmax; |s|<~12 so safe)
__device__ __forceinline__ float p0e(float s1, float s2, float E1, float E2) {
  float p = fmaf(E1, __expf(s1), fmaf(E2, __expf(s2), EPSF));
  float p2 = p * p, p4 = p2 * p2, p5 = p4 * p;
  return p5 * p5;
}

// ---------------- kernel 0: QKV projection (d-major, Q pre-scaled) + R/C init ----------------
__global__ __launch_bounds__(256) void qkv_kernel(
    const float* __restrict__ x,
    const float* __restrict__ Wq, const float* __restrict__ bq,
    const float* __restrict__ Wk, const float* __restrict__ bk,
    const float* __restrict__ Wv, const float* __restrict__ bv,
    float* __restrict__ Qt, float* __restrict__ Kt, float* __restrict__ Vt,
    float* __restrict__ R, float* __restrict__ CA, float* __restrict__ CB) {
  int row = blockIdx.x * 256 + threadIdx.x;     // 65536 rows
  int b = row >> 10, i = row & 1023;
  float xv[14];
#pragma unroll
  for (int k = 0; k < 14; k++) xv[k] = x[row * 14 + k];
#pragma unroll
  for (int d = 0; d < 14; d++) {
    float q = bq[d], kk = bk[d], vv = bv[d];
#pragma unroll
    for (int k = 0; k < 14; k++) {
      q  = fmaf(xv[k], Wq[d * 14 + k], q);
      kk = fmaf(xv[k], Wk[d * 14 + k], kk);
      vv = fmaf(xv[k], Wv[d * 14 + k], vv);
    }
    int o = b * 14336 + d * 1024 + i;
    Qt[o] = q * SCALEF;
    Kt[o] = kk; Vt[o] = vv;
  }
  R[row] = 1.0f;
  CA[row] = 1.0f;
  CB[row] = 1.0f;
}

// ---------------- kernel 1: attention + entropy/certainty + E1/E2 + FUSED out-proj ----------------
// 256 thr = 4 waves x 2 rows = 8 rows/block, grid 8192. Single score pass (exps stored
// in registers — 256-VGPR budget via launch_bounds(256,2)), entropy pass register-only.
// Output projection fused: lanes 0..13 each produce one out column from LDS Wo.
__global__ __launch_bounds__(256, 2) void attn_kernel(
    const float* __restrict__ Qt, const float* __restrict__ Kt, const float* __restrict__ Vt,
    const float* __restrict__ cert_in,
    const float* __restrict__ WoG, const float* __restrict__ boG,
    float* __restrict__ E1o, float* __restrict__ E2o,
    float* __restrict__ out_, float* __restrict__ cert_out) {
  __shared__ float4 Kl[3584];                   // 56 KB
  __shared__ float WoS[196];
  __shared__ float boS[14];
  int b = blockIdx.x >> 7;                      // 128 blocks per batch
  int rg = blockIdx.x & 127;                    // 8 rows per block
  int tid = threadIdx.x;
  const float4* Ktb = (const float4*)(Kt + b * 14336);
  for (int idx = tid; idx < 3584; idx += 256) Kl[idx] = Ktb[idx];
  if (tid < 196) WoS[tid] = WoG[tid];
  if (tid < 14) boS[tid] = boG[tid];
  __syncthreads();

  int wave = tid >> 6, lane = tid & 63;
  int i0 = rg * 8 + wave * 2;
  float q0[14], q1[14];
#pragma unroll
  for (int d = 0; d < 14; d++) {
    q0[d] = Qt[b * 14336 + d * 1024 + i0];
    q1[d] = Qt[b * 14336 + d * 1024 + i0 + 1];
  }

  // single pass: dots -> exps (stored) -> L sums + PV accumulation
  float4 e10[4], e20[4], e11[4], e21[4];        // [t]: row0 h1, row0 h2, row1 h1, row1 h2
  float L10 = 0.f, L20 = 0.f, L11 = 0.f, L21 = 0.f;
  float acc0[14], acc1[14];
#pragma unroll
  for (int d = 0; d < 14; d++) { acc0[d] = 0.f; acc1[d] = 0.f; }
  const float4* Vtb = (const float4*)(Vt + b * 14336);
#pragma unroll
  for (int t = 0; t < 4; t++) {
    int g = t * 64 + lane;
    float4 kv[7];
#pragma unroll
    for (int d = 0; d < 7; d++) kv[d] = Kl[d * 256 + g];
    float4 sa = {0,0,0,0}, sb = {0,0,0,0};
#pragma unroll
    for (int d = 0; d < 7; d++) { fma4(q0[d], kv[d], sa); fma4(q1[d], kv[d], sb); }
    e10[t] = exp4(sa); e11[t] = exp4(sb);
    L10 += e10[t].x + e10[t].y + e10[t].z + e10[t].w;
    L11 += e11[t].x + e11[t].y + e11[t].z + e11[t].w;
#pragma unroll
    for (int d = 0; d < 7; d++) kv[d] = Kl[(d + 7) * 256 + g];
    sa = make_float4(0,0,0,0); sb = make_float4(0,0,0,0);
#pragma unroll
    for (int d = 0; d < 7; d++) { fma4(q0[d + 7], kv[d], sa); fma4(q1[d + 7], kv[d], sb); }
    e20[t] = exp4(sa); e21[t] = exp4(sb);
    L20 += e20[t].x + e20[t].y + e20[t].z + e20[t].w;
    L21 += e21[t].x + e21[t].y + e21[t].z + e21[t].w;
#pragma unroll
    for (int d = 0; d < 7; d++) {
      float4 vv = Vtb[d * 256 + g];
      acc0[d] += e10[t].x * vv.x + e10[t].y * vv.y + e10[t].z * vv.z + e10[t].w * vv.w;
      acc1[d] += e11[t].x * vv.x + e11[t].y * vv.y + e11[t].z * vv.z + e11[t].w * vv.w;
    }
#pragma unroll
    for (int d = 7; d < 14; d++) {
      float4 vv = Vtb[d * 256 + g];
      acc0[d] += e20[t].x * vv.x + e20[t].y * vv.y + e20[t].z * vv.z + e20[t].w * vv.w;
      acc1[d] += e21[t].x * vv.x + e21[t].y * vv.y + e21[t].z * vv.z + e21[t].w * vv.w;
    }
  }
  wave_sum2(L10, L20); wave_sum2(L11, L21);
  float i10 = 1.0f / L10, i20 = 1.0f / L20, i11 = 1.0f / L11, i21 = 1.0f / L21;

  // entropy pass: registers only
  float ent0 = 0.f, ent1 = 0.f;
#pragma unroll
  for (int t = 0; t < 4; t++) {
    float a;
    a = 0.5f * (e10[t].x * i10 + e20[t].x * i20); ent0 -= a * __logf(a + EPSF);
    a = 0.5f * (e10[t].y * i10 + e20[t].y * i20); ent0 -= a * __logf(a + EPSF);
    a = 0.5f * (e10[t].z * i10 + e20[t].z * i20); ent0 -= a * __logf(a + EPSF);
    a = 0.5f * (e10[t].w * i10 + e20[t].w * i20); ent0 -= a * __logf(a + EPSF);
    a = 0.5f * (e11[t].x * i11 + e21[t].x * i21); ent1 -= a * __logf(a + EPSF);
    a = 0.5f * (e11[t].y * i11 + e21[t].y * i21); ent1 -= a * __logf(a + EPSF);
    a = 0.5f * (e11[t].z * i11 + e21[t].z * i21); ent1 -= a * __logf(a + EPSF);
    a = 0.5f * (e11[t].w * i11 + e21[t].w * i21); ent1 -= a * __logf(a + EPSF);
  }
  wave_sum2(ent0, ent1);
#pragma unroll
  for (int d = 0; d < 14; d += 2) wave_sum2(acc0[d], acc0[d + 1]);
#pragma unroll
  for (int d = 0; d < 14; d += 2) wave_sum2(acc1[d], acc1[d + 1]);

  int row0 = b * 1024 + i0;
  if (lane == 0) {
    E1o[row0] = 0.5f * i10;  E2o[row0] = 0.5f * i20;
    E1o[row0 + 1] = 0.5f * i11; E2o[row0 + 1] = 0.5f * i21;
    cert_out[row0] = fmaxf(cert_in[row0], 1.0f / (1.0f + __expf(ent0 - MAXENT)));
    cert_out[row0 + 1] = fmaxf(cert_in[row0 + 1], 1.0f / (1.0f + __expf(ent1 - MAXENT)));
  }
  // fused out-projection (wave_sum left acc in ALL lanes)
  if (lane < 14) {
    int d = lane;
    float av0[14], av1[14];
#pragma unroll
    for (int k = 0; k < 14; k++) {
      av0[k] = acc0[k] * (k < 7 ? i10 : i20);
      av1[k] = acc1[k] * (k < 7 ? i11 : i21);
    }
    float s0 = boS[d], s1 = boS[d];
#pragma unroll
    for (int k = 0; k < 14; k++) {
      s0 = fmaf(av0[k], WoS[d * 14 + k], s0);
      s1 = fmaf(av1[k], WoS[d * 14 + k], s1);
    }
    out_[(size_t)row0 * 14 + d] = s0;
    out_[(size_t)(row0 + 1) * 14 + d] = s1;
  }
}

// ================= FAST PATH: grouped materialized P0 =================

// fused P0 precompute + Sinkhorn iteration 1 (C_0 = 1):
__global__ __launch_bounds__(512) void p0sink1_kernel(
    const float* __restrict__ Qt, const float* __restrict__ Kt,
    const float* __restrict__ E1, const float* __restrict__ E2,
    float* __restrict__ P0, float* __restrict__ R,
    float* __restrict__ vpart, int b0, int G) {
  __shared__ float4 Kl[3584];                   // K tile, then reused as v-merge buf
  int gb = blockIdx.x >> 5, blk = blockIdx.x & 31;
  int b = b0 + gb;
  int tid = threadIdx.x;
  const float4* Ktb = (const float4*)(Kt + b * 14336);
  for (int idx = tid; idx < 3584; idx += 512) Kl[idx] = Ktb[idx];
  __syncthreads();

  int wave = tid >> 6, lane = tid & 63;
  int i0 = blk * 32 + wave * 4;
  float q[4][14], e1r[4], e2r[4], u[4];
#pragma unroll
  for (int rr = 0; rr < 4; rr++) {
#pragma unroll
    for (int d = 0; d < 14; d++) q[rr][d] = Qt[b * 14336 + d * 1024 + i0 + rr];
    e1r[rr] = E1[b * 1024 + i0 + rr];
    e2r[rr] = E2[b * 1024 + i0 + rr];
    u[rr] = 0.f;
  }
  float4* P0f4 = (float4*)P0;
#pragma unroll
  for (int t = 0; t < 4; t++) {
    int g = t * 64 + lane;
    float4 kv[14];
#pragma unroll
    for (int d = 0; d < 14; d++) kv[d] = Kl[d * 256 + g];
#pragma unroll
    for (int rr = 0; rr < 4; rr++) {
      float4 s1 = {0,0,0,0}, s2 = {0,0,0,0};
#pragma unroll
      for (int d = 0; d < 7; d++)  fma4(q[rr][d], kv[d], s1);
#pragma unroll
      for (int d = 7; d < 14; d++) fma4(q[rr][d], kv[d], s2);
      float4 pv;
      pv.x = p0e(s1.x, s2.x, e1r[rr], e2r[rr]);
      pv.y = p0e(s1.y, s2.y, e1r[rr], e2r[rr]);
      pv.z = p0e(s1.z, s2.z, e1r[rr], e2r[rr]);
      pv.w = p0e(s1.w, s2.w, e1r[rr], e2r[rr]);
      P0f4[(size_t)(gb * 1024 + i0 + rr) * 256 + g] = pv;
      u[rr] += pv.x; u[rr] += pv.y; u[rr] += pv.z; u[rr] += pv.w;
    }
  }
  wave_sum2(u[0], u[1]); wave_sum2(u[2], u[3]);
  float rv[4];
#pragma unroll
  for (int rr = 0; rr < 4; rr++) {
    float r0 = 1.0f;
    rv[rr] = fminf(r0 / fmaf(r0, u[rr], EPSF), 1e37f);
  }
  if (lane == 0) {
#pragma unroll
    for (int rr = 0; rr < 4; rr++) R[b * 1024 + i0 + rr] = rv[rr];
  }
  int l0 = lane, l1 = 64 + lane, l2 = 128 + lane, l3 = 192 + lane;
  float4 v0 = {0,0,0,0}, v1 = {0,0,0,0}, v2 = {0,0,0,0}, v3 = {0,0,0,0};
  const float4* base = P0f4 + (size_t)(gb * 1024 + i0) * 256;
#pragma unroll
  for (int rr = 0; rr < 4; rr++) {
    const float4* row = base + rr * 256;
    float4 a0 = row[l0], a1 = row[l1], a2 = row[l2], a3 = row[l3];
    fma4(rv[rr], a0, v0); fma4(rv[rr], a1, v1); fma4(rv[rr], a2, v2); fma4(rv[rr], a3, v3);
  }
  __syncthreads();
  float* vbuf = (float*)Kl;
  float4* vb4 = (float4*)vbuf;
  vb4[wave * 256 + l0] = v0; vb4[wave * 256 + l1] = v1;
  vb4[wave * 256 + l2] = v2; vb4[wave * 256 + l3] = v3;
  __syncthreads();
  for (int col = tid; col < 1024; col += 512) {
    float v = 0.f;
#pragma unroll
    for (int w = 0; w < 8; w++) v += vbuf[w * 1024 + col];
    vpart[(size_t)(blk * G + gb) * 1024 + col] = v;
  }
}

// fused Sinkhorn iteration (round-8 proven shape)
#define SINK_LOGS 4
#define SINK_S    16
__global__ __launch_bounds__(512) void sink_fused(
    const float* __restrict__ P0, const float* __restrict__ Cin,
    float* __restrict__ Cout, float* __restrict__ R,
    const float* __restrict__ vprev, float* __restrict__ vcur,
    int b0, int G, int Sprev) {
  __shared__ float Cl[1024];
  __shared__ float vbuf[8192];
  int tid = threadIdx.x;
  int gb = blockIdx.x >> SINK_LOGS, slice = blockIdx.x & (SINK_S - 1);
  int b = b0 + gb;

  if (tid < 256) {
    float4 cv = ((const float4*)(Cin + b * 1024))[tid];
    const float4* vp = (const float4*)vprev + (size_t)gb * 256 + tid;
    float4 v = {0, 0, 0, 0};
#pragma unroll 4
    for (int s = 0; s < Sprev; s++) {
      float4 t = vp[(size_t)s * G * 256];
      v.x += t.x; v.y += t.y; v.z += t.z; v.w += t.w;
    }
    cv.x = fminf(cv.x / fmaf(cv.x, v.x, EPSF), 1e37f);
    cv.y = fminf(cv.y / fmaf(cv.y, v.y, EPSF), 1e37f);
    cv.z = fminf(cv.z / fmaf(cv.z, v.z, EPSF), 1e37f);
    cv.w = fminf(cv.w / fmaf(cv.w, v.w, EPSF), 1e37f);
    if (slice == 0) ((float4*)(Cout + b * 1024))[tid] = cv;
    ((float4*)Cl)[tid] = cv;
  }
  __syncthreads();

  int wave = tid >> 6, lane = tid & 63;
  int i0 = slice * 64 + wave * 8;
  int rbase = b * 1024 + i0;
  int l0 = lane, l1 = 64 + lane, l2 = 128 + lane, l3 = 192 + lane;
  const float4* Cl4 = (const float4*)Cl;
  float4 c0 = Cl4[l0], c1 = Cl4[l1], c2 = Cl4[l2], c3 = Cl4[l3];
  float4 v0 = {0,0,0,0}, v1 = {0,0,0,0}, v2 = {0,0,0,0}, v3 = {0,0,0,0};
  const float4* base = (const float4*)P0 + (size_t)(gb * 1024 + i0) * 256;

  float rreg[8];
#pragma unroll
  for (int r = 0; r < 8; r++) rreg[r] = R[rbase + r];

  float4 a0 = base[l0], a1 = base[l1], a2 = base[l2], a3 = base[l3];
  float4 b0f = base[256 + l0], b1f = base[256 + l1], b2f = base[256 + l2], b3f = base[256 + l3];

#pragma unroll
  for (int r = 0; r < 8; r += 2) {
    float4 na0, na1, na2, na3, nb0, nb1, nb2, nb3;
    if (r + 2 < 8) {
      const float4* nxt = base + (r + 2) * 256;
      na0 = nxt[l0]; na1 = nxt[l1]; na2 = nxt[l2]; na3 = nxt[l3];
      nb0 = nxt[256 + l0]; nb1 = nxt[256 + l1]; nb2 = nxt[256 + l2]; nb3 = nxt[256 + l3];
    }
    float ua = dot4(a3, c3, dot4(a2, c2, dot4(a1, c1, dot4(a0, c0, 0.f))));
    float ub = dot4(b3f, c3, dot4(b2f, c2, dot4(b1f, c1, dot4(b0f, c0, 0.f))));
    wave_sum2(ua, ub);
    float rva = rreg[r], rvb = rreg[r + 1];
    rva = fminf(rva / fmaf(rva, ua, EPSF), 1e37f);
    rvb = fminf(rvb / fmaf(rvb, ub, EPSF), 1e37f);
    if (lane == 0) { R[rbase + r] = rva; R[rbase + r + 1] = rvb; }
    fma4(rva, a0, v0); fma4(rva, a1, v1); fma4(rva, a2, v2); fma4(rva, a3, v3);
    fma4(rvb, b0f, v0); fma4(rvb, b1f, v1); fma4(rvb, b2f, v2); fma4(rvb, b3f, v3);
    if (r + 2 < 8) {
      a0 = na0; a1 = na1; a2 = na2; a3 = na3;
      b0f = nb0; b1f = nb1; b2f = nb2; b3f = nb3;
    }
  }
  float4* vb4 = (float4*)vbuf;
  vb4[wave * 256 + l0] = v0; vb4[wave * 256 + l1] = v1;
  vb4[wave * 256 + l2] = v2; vb4[wave * 256 + l3] = v3;
  __syncthreads();
  for (int col = tid; col < 1024; col += 512) {
    float v = 0.f;
#pragma unroll
    for (int w = 0; w < 8; w++) v += vbuf[w * 1024 + col];
    vcur[(size_t)(slice * G + gb) * 1024 + col] = v;
  }
}

// final C_20 = f(C_19, v_20)
__global__ __launch_bounds__(256) void cfinal_kernel(
    const float* __restrict__ Cin, float* __restrict__ Cfin,
    const float* __restrict__ vprev, int b0, int G) {
  int idx = blockIdx.x * 256 + threadIdx.x;
  int gb = idx >> 10, col = idx & 1023;
  const float* vp = vprev + gb * 1024 + col;
  float v = 0.f;
#pragma unroll
  for (int s = 0; s < SINK_S; s++) v += vp[(size_t)s * G * 1024];
  int o = (b0 + gb) * 1024 + col;
  float cv = Cin[o];
  Cfin[o] = fminf(cv / fmaf(cv, v, EPSF), 1e37f);
}

// argmax over stored P0 * C + permutation gather; grid = G*128
__global__ __launch_bounds__(512) void argmaxP_kernel(
    const float* __restrict__ P0, const float* __restrict__ Cg,
    const int* __restrict__ perm, float* __restrict__ perm_out, int b0) {
  int gb = blockIdx.x >> 7, rg = blockIdx.x & 127;
  int b = b0 + gb;
  int tid = threadIdx.x;
  int wave = tid >> 6, lane = tid & 63;
  int i = rg * 8 + wave;
  const float4* Cb = (const float4*)(Cg + b * 1024);
  const float4* Prow = (const float4*)P0 + (size_t)(gb * 1024 + i) * 256;

  float best = -1.0f;
  int bj = 0;
#pragma unroll
  for (int t = 0; t < 4; t++) {
    int g = t * 64 + lane;
    float4 pv = Prow[g], cv = Cb[g];
    float val;
    val = pv.x * cv.x; if (val > best) { best = val; bj = 4 * g + 0; }
    val = pv.y * cv.y; if (val > best) { best = val; bj = 4 * g + 1; }
    val = pv.z * cv.z; if (val > best) { best = val; bj = 4 * g + 2; }
    val = pv.w * cv.w; if (val > best) { best = val; bj = 4 * g + 3; }
  }
#pragma unroll
  for (int off = 32; off > 0; off >>= 1) {
    float ob = __shfl_xor(best, off);
    int oj = __shfl_xor(bj, off);
    if (ob > best || (ob == best && oj < bj)) { best = ob; bj = oj; }
  }
  if (lane == 0) perm_out[b * 1024 + i] = (float)perm[b * 1024 + bj];
}

// ================= FALLBACK PATH (recompute) =================

__global__ __launch_bounds__(512) void sinkA_kernel(
    const float* __restrict__ Qt, const float* __restrict__ Kt,
    const float* __restrict__ E1, const float* __restrict__ E2,
    const float* __restrict__ C, float* __restrict__ R) {
  __shared__ float4 Kl[3584];
  int b = blockIdx.x >> 5, blk = blockIdx.x & 31;
  int tid = threadIdx.x;
  const float4* Ktb = (const float4*)(Kt + b * 14336);
  for (int idx = tid; idx < 3584; idx += 512) Kl[idx] = Ktb[idx];
  __syncthreads();
  int wave = tid >> 6, lane = tid & 63;
  int i0 = blk * 32 + wave * 4;
  float q[4][14], e1r[4], e2r[4], u[4];
#pragma unroll
  for (int rr = 0; rr < 4; rr++) {
#pragma unroll
    for (int d = 0; d < 14; d++) q[rr][d] = Qt[b * 14336 + d * 1024 + i0 + rr];
    e1r[rr] = E1[b * 1024 + i0 + rr];
    e2r[rr] = E2[b * 1024 + i0 + rr];
    u[rr] = 0.f;
  }
  const float4* Cb = (const float4*)(C + b * 1024);
#pragma unroll
  for (int t = 0; t < 4; t++) {
    int g = t * 64 + lane;
    float4 kv[14];
#pragma unroll
    for (int d = 0; d < 14; d++) kv[d] = Kl[d * 256 + g];
    float4 cv = Cb[g];
#pragma unroll
    for (int rr = 0; rr < 4; rr++) {
      float4 s1 = {0,0,0,0}, s2 = {0,0,0,0};
#pragma unroll
      for (int d = 0; d < 7; d++)  fma4(q[rr][d], kv[d], s1);
#pragma unroll
      for (int d = 7; d < 14; d++) fma4(q[rr][d], kv[d], s2);
      u[rr] += p0e(s1.x, s2.x, e1r[rr], e2r[rr]) * cv.x;
      u[rr] += p0e(s1.y, s2.y, e1r[rr], e2r[rr]) * cv.y;
      u[rr] += p0e(s1.z, s2.z, e1r[rr], e2r[rr]) * cv.z;
      u[rr] += p0e(s1.w, s2.w, e1r[rr], e2r[rr]) * cv.w;
    }
  }
#pragma unroll
  for (int rr = 0; rr < 4; rr++) u[rr] = wave_sum(u[rr]);
  if (lane == 0) {
#pragma unroll
    for (int rr = 0; rr < 4; rr++) {
      int o = b * 1024 + i0 + rr;
      float rv = R[o];
      R[o] = fminf(rv / fmaf(rv, u[rr], EPSF), 1e37f);
    }
  }
}

__global__ __launch_bounds__(512) void sinkB_kernel(
    const float* __restrict__ Qt, const float* __restrict__ Kt,
    const float* __restrict__ E1, const float* __restrict__ E2,
    const float* __restrict__ R, float* __restrict__ C) {
  __shared__ float4 Ql[3584];
  int b = blockIdx.x >> 5, blk = blockIdx.x & 31;
  int tid = threadIdx.x;
  const float4* Qtb = (const float4*)(Qt + b * 14336);
  for (int idx = tid; idx < 3584; idx += 512) Ql[idx] = Qtb[idx];
  __syncthreads();
  int wave = tid >> 6, lane = tid & 63;
  int j0 = blk * 32 + wave * 4;
  float kk[4][14], v[4];
#pragma unroll
  for (int rr = 0; rr < 4; rr++) {
#pragma unroll
    for (int d = 0; d < 14; d++) kk[rr][d] = Kt[b * 14336 + d * 1024 + j0 + rr];
    v[rr] = 0.f;
  }
  const float4* E1b = (const float4*)(E1 + b * 1024);
  const float4* E2b = (const float4*)(E2 + b * 1024);
  const float4* Rb  = (const float4*)(R + b * 1024);
#pragma unroll
  for (int t = 0; t < 4; t++) {
    int g = t * 64 + lane;
    float4 qv[14];
#pragma unroll
    for (int d = 0; d < 14; d++) qv[d] = Ql[d * 256 + g];
    float4 e1v = E1b[g], e2v = E2b[g], rv = Rb[g];
#pragma unroll
    for (int rr = 0; rr < 4; rr++) {
      float4 s1 = {0,0,0,0}, s2 = {0,0,0,0};
#pragma unroll
      for (int d = 0; d < 7; d++)  fma4(kk[rr][d], qv[d], s1);
#pragma unroll
      for (int d = 7; d < 14; d++) fma4(kk[rr][d], qv[d], s2);
      v[rr] += p0e(s1.x, s2.x, e1v.x, e2v.x) * rv.x;
      v[rr] += p0e(s1.y, s2.y, e1v.y, e2v.y) * rv.y;
      v[rr] += p0e(s1.z, s2.z, e1v.z, e2v.z) * rv.z;
      v[rr] += p0e(s1.w, s2.w, e1v.w, e2v.w) * rv.w;
    }
  }
#pragma unroll
  for (int rr = 0; rr < 4; rr++) v[rr] = wave_sum(v[rr]);
  if (lane == 0) {
#pragma unroll
    for (int rr = 0; rr < 4; rr++) {
      int o = b * 1024 + j0 + rr;
      float cv = C[o];
      C[o] = fminf(cv / fmaf(cv, v[rr], EPSF), 1e37f);
    }
  }
}

__global__ __launch_bounds__(512) void argmax_kernel(
    const float* __restrict__ Qt, const float* __restrict__ Kt,
    const float* __restrict__ E1, const float* __restrict__ E2,
    const float* __restrict__ C, const int* __restrict__ perm,
    float* __restrict__ perm_out) {
  __shared__ float4 Kl[3584];
  int b = blockIdx.x >> 7, rg = blockIdx.x & 127;
  int tid = threadIdx.x;
  const float4* Ktb = (const float4*)(Kt + b * 14336);
  for (int idx = tid; idx < 3584; idx += 512) Kl[idx] = Ktb[idx];
  __syncthreads();
  int wave = tid >> 6, lane = tid & 63;
  int i = rg * 8 + wave;
  int row = b * 1024 + i;
  float q[14];
#pragma unroll
  for (int d = 0; d < 14; d++) q[d] = Qt[b * 14336 + d * 1024 + i];
  float e1r = E1[row], e2r = E2[row];
  const float4* Cb = (const float4*)(C + b * 1024);
  float best = -1.0f;
  int bj = 0;
#pragma unroll
  for (int t = 0; t < 4; t++) {
    int g = t * 64 + lane;
    float4 kv[14];
#pragma unroll
    for (int d = 0; d < 14; d++) kv[d] = Kl[d * 256 + g];
    float4 cv = Cb[g];
    float4 s1 = {0,0,0,0}, s2 = {0,0,0,0};
#pragma unroll
    for (int d = 0; d < 7; d++)  fma4(q[d], kv[d], s1);
#pragma unroll
    for (int d = 7; d < 14; d++) fma4(q[d], kv[d], s2);
    float val;
    val = p0e(s1.x, s2.x, e1r, e2r) * cv.x; if (val > best) { best = val; bj = 4 * g + 0; }
    val = p0e(s1.y, s2.y, e1r, e2r) * cv.y; if (val > best) { best = val; bj = 4 * g + 1; }
    val = p0e(s1.z, s2.z, e1r, e2r) * cv.z; if (val > best) { best = val; bj = 4 * g + 2; }
    val = p0e(s1.w, s2.w, e1r, e2r) * cv.w; if (val > best) { best = val; bj = 4 * g + 3; }
  }
#pragma unroll
  for (int off = 32; off > 0; off >>= 1) {
    float ob = __shfl_xor(best, off);
    int oj = __shfl_xor(bj, off);
    if (ob > best || (ob == best && oj < bj)) { best = ob; bj = oj; }
  }
  if (lane == 0) perm_out[row] = (float)perm[b * 1024 + bj];
}

// ---------------- launch ----------------
extern "C" void kernel_launch(void* const* d_in, const int* in_sizes, int n_in,
                              void* d_out, int out_size, void* d_ws, size_t ws_size,
                              hipStream_t stream) {
  const float* x    = (const float*)d_in[0];
  const float* cert = (const float*)d_in[1];
  const int*   perm = (const int*)d_in[2];
  const float* Wq = (const float*)d_in[3];
  const float* bq = (const float*)d_in[4];
  const float* Wk = (const float*)d_in[5];
  const float* bk = (const float*)d_in[6];
  const float* Wv = (const float*)d_in[7];
  const float* bv = (const float*)d_in[8];
  const float* Wo = (const float*)d_in[9];
  const float* bo = (const float*)d_in[10];

  float* out      = (float*)d_out;            // 917504
  float* cert_out = out + 917504;             // 65536
  float* perm_out = out + 983040;             // 65536

  float* ws = (float*)d_ws;
  float* Qt = ws;                    // 917504
  float* Kt = Qt + 917504;           // 917504
  float* Vt = Kt + 917504;           // 917504
  float* E1 = Vt + 917504;           // 65536
  float* E2 = E1 + 65536;            // 65536
  float* R  = E2 + 65536;            // 65536
  float* CA = R + 65536;             // 65536  (C ping)
  float* CB = CA + 65536;            // 65536  (C pong)
  float* vpp0 = CB + 65536;          // 32*G*1024 each buffer (base ends: 3,080,192)

  // choose batch-group size G by available workspace
  size_t base_f = 3080192u;
  size_t avail_f = (ws_size / 4 > base_f) ? (ws_size / 4 - base_f) : 0;
  size_t perG = 2u * 32 * 1024 + 1048576u;      // vpart x2 + P0 floats per batch
  int G = 0;
  if (avail_f >= 64 * perG) G = 64;
  else if (avail_f >= 32 * perG) G = 32;
  else if (avail_f >= 16 * perG) G = 16;

  float* Cbuf[2] = {CA, CB};

  qkv_kernel<<<256, 256, 0, stream>>>(x, Wq, bq, Wk, bk, Wv, bv, Qt, Kt, Vt, R, CA, CB);
  attn_kernel<<<8192, 256, 0, stream>>>(Qt, Kt, Vt, cert, Wo, bo, E1, E2, out, cert_out);

  if (G >= 16) {
    float* vpp[2] = {vpp0, vpp0 + (size_t)32 * G * 1024};
    float* P0 = vpp0 + (size_t)2 * 32 * G * 1024;
    for (int b0 = 0; b0 < 64; b0 += G) {
      // iteration 1 fused with P0 precompute; writes v_1 (32 slices) into vpp[1]
      p0sink1_kernel<<<G * 32, 512, 0, stream>>>(Qt, Kt, E1, E2, P0, R, vpp[1], b0, G);
      for (int it = 2; it <= 20; it++) {
        const float* vprev = vpp[(it - 1) & 1];
        float* vcur = vpp[it & 1];
        const float* Cin = Cbuf[it & 1];
        float* Cout = Cbuf[(it + 1) & 1];
        int Sprev = (it == 2) ? 32 : 16;
        sink_fused<<<G * SINK_S, 512, 0, stream>>>(P0, Cin, Cout, R, vprev, vcur, b0, G, Sprev);
      }
      cfinal_kernel<<<G * 4, 256, 0, stream>>>(Cbuf[1], Cbuf[0], vpp[0], b0, G);
      argmaxP_kernel<<<G * 128, 512, 0, stream>>>(P0, Cbuf[0], perm, perm_out, b0);
    }
  } else {
    for (int it = 0; it < 20; it++) {
      sinkA_kernel<<<2048, 512, 0, stream>>>(Qt, Kt, E1, E2, CA, R);
      sinkB_kernel<<<2048, 512, 0, stream>>>(Qt, Kt, E1, E2, R, CA);
    }
    argmax_kernel<<<8192, 512, 0, stream>>>(Qt, Kt, E1, E2, CA, perm, perm_out);
  }
}